// Round 7
// baseline (25.459 us; speedup 1.0000x reference)
//
#include <hip/hip_runtime.h>
#include <math.h>

#define HDIM 32
#define NSTEPS 32
#define NSECANT 8
#define RADIUSV 1.0f
#define NEARV 0.5f
#define TAUV 0.5f
#define EPSV 1e-6f
#define MARGINV 0.03f   // f16-coarse ambiguity margin (empirical err ~3e-3 RMS)

typedef float f2 __attribute__((ext_vector_type(2)));
typedef _Float16 h2 __attribute__((ext_vector_type(2)));

__global__ __launch_bounds__(256, 2) void unisurf_kernel(
    const float* __restrict__ cam_loc,   // [3]
    const float* __restrict__ ray_dirs,  // [P*3]
    const float* __restrict__ W1,        // [3*HDIM]
    const float* __restrict__ b1,        // [HDIM]
    const float* __restrict__ W2,        // [HDIM]
    const float* __restrict__ b2,        // [1]
    float* __restrict__ out,             // [2*P]: d_pred then occ_surf
    int P)
{
    __shared__ float4 sW[HDIM];   // (w0, w1, w2, b1) per hidden unit
    __shared__ float  sCW[HDIM];  // cam·W1 + b1  (ray-independent)
    __shared__ float  sW2[HDIM];
    __shared__ float  sB2;

    const int tid = threadIdx.x;
    if (tid < HDIM) {
        float c0 = cam_loc[0], c1 = cam_loc[1], c2l = cam_loc[2];
        float4 w4 = make_float4(W1[tid], W1[HDIM + tid], W1[2 * HDIM + tid], b1[tid]);
        sW[tid] = w4;
        sCW[tid] = c0 * w4.x + c1 * w4.y + c2l * w4.z + w4.w;
        sW2[tid] = W2[tid];
        if (tid == 0) sB2 = b2[0];
    }
    __syncthreads();

    const int r = blockIdx.x * blockDim.x + tid;
    if (r >= P) return;

    // camera (wave-uniform)
    const float cx = cam_loc[0], cy = cam_loc[1], cz = cam_loc[2];

    // ray load + fast normalize
    float dx = ray_dirs[3 * r + 0];
    float dy = ray_dirs[3 * r + 1];
    float dz = ray_dirs[3 * r + 2];
    float inv = __builtin_amdgcn_rsqf(dx * dx + dy * dy + dz * dz);
    float rx = dx * inv, ry = dy * inv, rz = dz * inv;

    // sphere intersection
    float rcd = rx * cx + ry * cy + rz * cz;
    float c2  = cx * cx + cy * cy + cz * cz;
    float us  = rcd * rcd - (c2 - RADIUSV * RADIUSV);
    bool  mask_int = us > 0.0f;
    float s_sq = mask_int ? sqrtf(us) : 0.0f;
    float far_raw = mask_int ? fmaxf(s_sq - rcd, 0.0f) : 0.0f;
    float farv = fmaxf(far_raw, NEARV + EPSV);

    // per-ray factored MLP: a_h(d) = cW[h] + d*rW[h]; logit = Σ relu(a)*w2 + B2
    f2 rW[HDIM / 2], cW[HDIM / 2], w2[HDIM / 2];     // f32 (secant/fallback)
    h2 rWh[HDIM / 2], cWh[HDIM / 2], w2h[HDIM / 2];  // f16 (coarse)
    #pragma unroll
    for (int h = 0; h < HDIM / 2; ++h) {
        float4 wa = sW[2 * h], wb = sW[2 * h + 1];
        rW[h] = (f2){rx * wa.x + ry * wa.y + rz * wa.z,
                     rx * wb.x + ry * wb.y + rz * wb.z};
        cW[h] = (f2){sCW[2 * h], sCW[2 * h + 1]};
        w2[h] = (f2){sW2[2 * h], sW2[2 * h + 1]};
        rWh[h] = (h2){(_Float16)rW[h].x, (_Float16)rW[h].y};
        cWh[h] = (h2){(_Float16)cW[h].x, (_Float16)cW[h].y};
        w2h[h] = (h2){(_Float16)w2[h].x, (_Float16)w2[h].y};
    }
    const float B2 = sB2;
    const f2 z2 = (f2){0.0f, 0.0f};
    const h2 zh = (h2){(_Float16)0.0f, (_Float16)0.0f};

    // f16 packed logit, f32 accumulate via v_dot2_f32_f16; 2 evals interleaved
    auto logit2h = [&](float dA, float dB, float& lA, float& lB) {
        _Float16 hA = (_Float16)dA, hB = (_Float16)dB;
        h2 dvA = (h2){hA, hA}, dvB = (h2){hB, hB};
        float aA0 = 0.0f, aA1 = 0.0f, aB0 = 0.0f, aB1 = 0.0f;
        #pragma unroll
        for (int h = 0; h < HDIM / 2; h += 2) {
            h2 xA0 = __builtin_elementwise_fma(dvA, rWh[h + 0], cWh[h + 0]);
            h2 xB0 = __builtin_elementwise_fma(dvB, rWh[h + 0], cWh[h + 0]);
            h2 xA1 = __builtin_elementwise_fma(dvA, rWh[h + 1], cWh[h + 1]);
            h2 xB1 = __builtin_elementwise_fma(dvB, rWh[h + 1], cWh[h + 1]);
            aA0 = __builtin_amdgcn_fdot2(__builtin_elementwise_max(xA0, zh), w2h[h + 0], aA0, false);
            aB0 = __builtin_amdgcn_fdot2(__builtin_elementwise_max(xB0, zh), w2h[h + 0], aB0, false);
            aA1 = __builtin_amdgcn_fdot2(__builtin_elementwise_max(xA1, zh), w2h[h + 1], aA1, false);
            aB1 = __builtin_amdgcn_fdot2(__builtin_elementwise_max(xB1, zh), w2h[h + 1], aB1, false);
        }
        lA = (aA0 + aA1) + B2;
        lB = (aB0 + aB1) + B2;
    };
    // exact f32 logit pair (bracket)
    auto logit2 = [&](float dA, float dB, float& lA, float& lB) {
        f2 dvA = (f2){dA, dA}, dvB = (f2){dB, dB};
        f2 aA0 = z2, aA1 = z2, aB0 = z2, aB1 = z2;
        #pragma unroll
        for (int h = 0; h < HDIM / 2; h += 2) {
            f2 xA0 = __builtin_elementwise_fma(dvA, rW[h + 0], cW[h + 0]);
            f2 xB0 = __builtin_elementwise_fma(dvB, rW[h + 0], cW[h + 0]);
            f2 xA1 = __builtin_elementwise_fma(dvA, rW[h + 1], cW[h + 1]);
            f2 xB1 = __builtin_elementwise_fma(dvB, rW[h + 1], cW[h + 1]);
            aA0 = __builtin_elementwise_fma(__builtin_elementwise_max(xA0, z2), w2[h + 0], aA0);
            aB0 = __builtin_elementwise_fma(__builtin_elementwise_max(xB0, z2), w2[h + 0], aB0);
            aA1 = __builtin_elementwise_fma(__builtin_elementwise_max(xA1, z2), w2[h + 1], aA1);
            aB1 = __builtin_elementwise_fma(__builtin_elementwise_max(xB1, z2), w2[h + 1], aB1);
        }
        f2 sA = aA0 + aA1, sB = aB0 + aB1;
        lA = (sA.x + sA.y) + B2;
        lB = (sB.x + sB.y) + B2;
    };
    // exact f32 single logit (fallback, secant, final)
    auto logit = [&](float d) -> float {
        f2 dv = (f2){d, d};
        f2 a0 = z2, a1 = z2, a2 = z2, a3 = z2;
        #pragma unroll
        for (int h = 0; h < HDIM / 2; h += 4) {
            f2 x0 = __builtin_elementwise_fma(dv, rW[h + 0], cW[h + 0]);
            f2 x1 = __builtin_elementwise_fma(dv, rW[h + 1], cW[h + 1]);
            f2 x2 = __builtin_elementwise_fma(dv, rW[h + 2], cW[h + 2]);
            f2 x3 = __builtin_elementwise_fma(dv, rW[h + 3], cW[h + 3]);
            a0 = __builtin_elementwise_fma(__builtin_elementwise_max(x0, z2), w2[h + 0], a0);
            a1 = __builtin_elementwise_fma(__builtin_elementwise_max(x1, z2), w2[h + 1], a1);
            a2 = __builtin_elementwise_fma(__builtin_elementwise_max(x2, z2), w2[h + 2], a2);
            a3 = __builtin_elementwise_fma(__builtin_elementwise_max(x3, z2), w2[h + 3], a3);
        }
        f2 aa = (a0 + a1) + (a2 + a3);
        return (aa.x + aa.y) + B2;
    };
    auto sigm = [](float x) -> float {
        float e = __expf(-x);
        return __builtin_amdgcn_rcpf(1.0f + e);
    };

    const float STEPC = 0.03225806451612903f;  // fl(1/31)

    // coarse march in packed f16: 16 iters × 2 interleaved evals.
    // msk bit s = (logit_s >= 0); amb bit s = |logit_f16| < margin
    unsigned msk = 0u, amb = 0u;
    #pragma unroll 1
    for (int k = 0; k < 16; ++k) {
        float tA = (float)k * STEPC;
        float tB = (float)(k + 16) * STEPC;
        float dA = NEARV * (1.0f - tA) + farv * tA;
        float dB = NEARV * (1.0f - tB) + farv * tB;
        float lA, lB;
        logit2h(dA, dB, lA, lB);
        msk |= (lA >= 0.0f) ? (1u << k) : 0u;
        msk |= (lB >= 0.0f) ? (1u << (k + 16)) : 0u;
        amb |= (fabsf(lA) < MARGINV) ? (1u << k) : 0u;
        amb |= (fabsf(lB) < MARGINV) ? (1u << (k + 16)) : 0u;
    }

    // sparse f32 re-verification of ambiguous samples (rare; divergent ok)
    while (__builtin_amdgcn_ballot_w64(amb != 0u)) {
        if (amb != 0u) {
            int s = __builtin_ctz(amb);
            amb &= amb - 1u;
            float t = (float)s * STEPC;
            float dd = NEARV * (1.0f - t) + farv * t;
            float ls = logit(dd);
            unsigned bit = 1u << s;
            msk = (ls >= 0.0f) ? (msk | bit) : (msk & ~bit);
        }
    }

    // first free->occupied crossing: f[s]<0 && f[s+1]>=0
    unsigned cand = (~msk & (msk >> 1)) & 0x7FFFFFFFu;
    bool found = cand != 0u;
    int sstar = found ? __builtin_ctz(cand) : 0;   // ref: argmax(all-false)=0
    found = found && mask_int;

    // bracket endpoints (exact f32)
    float tlo = (float)sstar * STEPC;
    float thi = (float)(sstar + 1) * STEPC;
    float d_lo = NEARV * (1.0f - tlo) + farv * tlo;
    float d_hi = NEARV * (1.0f - thi) + farv * thi;
    float f_lo, f_hi;                 // logit-space secant state
    logit2(d_lo, d_hi, f_lo, f_hi);

    // secant refinement in logit space (root: sigmoid(l)=tau <=> l=0)
    #pragma unroll 1
    for (int it = 0; it < NSECANT; ++it) {
        float den = f_hi - f_lo;
        den = (fabsf(den) < EPSV) ? EPSV : den;
        float dm = d_lo - f_lo * (d_hi - d_lo) * __builtin_amdgcn_rcpf(den);
        float fm = logit(dm);
        bool neg = fm < 0.0f;
        d_lo = neg ? dm : d_lo;
        f_lo = neg ? fm : f_lo;
        d_hi = neg ? d_hi : dm;
        f_hi = neg ? f_hi : fm;
    }
    float den = f_hi - f_lo;
    den = (fabsf(den) < EPSV) ? EPSV : den;
    float d_mid = d_lo - f_lo * (d_hi - d_lo) * __builtin_amdgcn_rcpf(den);

    float d_pred = found ? d_mid : 0.0f;
    float occ_s = sigm(logit(d_pred));
    float occ_surf = found ? occ_s : 0.0f;

    out[r]     = d_pred;
    out[P + r] = occ_surf;
}

extern "C" void kernel_launch(void* const* d_in, const int* in_sizes, int n_in,
                              void* d_out, int out_size, void* d_ws, size_t ws_size,
                              hipStream_t stream) {
    const float* cam_loc  = (const float*)d_in[0];
    const float* ray_dirs = (const float*)d_in[1];
    const float* W1       = (const float*)d_in[2];
    const float* b1       = (const float*)d_in[3];
    const float* W2       = (const float*)d_in[4];
    const float* b2       = (const float*)d_in[5];
    float* out = (float*)d_out;

    const int P = in_sizes[1] / 3;
    const int block = 256;
    const int grid = (P + block - 1) / block;
    unisurf_kernel<<<grid, block, 0, stream>>>(cam_loc, ray_dirs, W1, b1, W2, b2, out, P);
}